// Round 2
// baseline (10414.684 us; speedup 1.0000x reference)
//
#include <hip/hip_runtime.h>
#include <hip/hip_bf16.h>
#include <stdint.h>

// ---------------------------------------------------------------------------
// 2-layer LSTM + linear + CRF NLL on MI355X.
// Round 10: attack the dependency-cycle STRUCTURE (R9 showed read path and
// barrier mechanics are both non-dominant):
//   1. 4-deep h rings (was 2): removes the L1->L0 slab-reuse feedback edge
//      from the critical cycle; critical path is now only L0's own chain.
//   2. L0 computes the x*Wih MFMA (1/3 of its work) BEFORE the wait; L1
//      splits its wait (own-layer poll -> Whh1 MFMA -> L0 poll -> Wih1 MFMA)
//      so Whh1 compute overlaps L0's store-drain + flag propagation.
//   3. Ring stores packed to 16B global_store_dwordx4 sc1 (64/block instead
//      of 256 scattered 4B) -> 4x fewer IC transactions before the drain
//      that gates the arrival flag. h1_all stores packed too.
//   4. sc1 (IC-direct) ring reads as in R8 (proven); no per-step buffer_inv,
//      so x_b stays L2-resident. Poll reductions split across waves 0/1.
// ---------------------------------------------------------------------------

typedef __bf16 bf16x8 __attribute__((ext_vector_type(8)));
typedef float f32x4 __attribute__((ext_vector_type(4)));
typedef unsigned u32x4 __attribute__((ext_vector_type(4)));

__device__ __forceinline__ f32x4 mfma16(bf16x8 a, bf16x8 b, f32x4 c) {
  return __builtin_amdgcn_mfma_f32_16x16x32_bf16(a, b, c, 0, 0, 0);
}

__device__ __forceinline__ unsigned short f2bf(float f) {
  unsigned u = __float_as_uint(f);
  u = u + 0x7fffu + ((u >> 16) & 1u);
  return (unsigned short)(u >> 16);
}
__device__ __forceinline__ float sigf(float x) { return 1.f / (1.f + __expf(-x)); }
__device__ __forceinline__ float tanh_s(float x) {
  float a = fabsf(x);
  float e = __expf(2.f * a);
  float r = 1.f - 2.f / (e + 1.f);
  return copysignf(r, x);
}
__device__ __forceinline__ bf16x8 cvt8(const float* p) {
  float4 a = *(const float4*)p;
  float4 b = *(const float4*)(p + 4);
  union { bf16x8 v; unsigned short u[8]; } r;
  r.u[0] = f2bf(a.x); r.u[1] = f2bf(a.y); r.u[2] = f2bf(a.z); r.u[3] = f2bf(a.w);
  r.u[4] = f2bf(b.x); r.u[5] = f2bf(b.y); r.u[6] = f2bf(b.z); r.u[7] = f2bf(b.w);
  return r.v;
}

// ---- agent-scope (IC-coherent) primitives ----
__device__ __forceinline__ unsigned ald32(const unsigned* p) {
  return __hip_atomic_load(p, __ATOMIC_RELAXED, __HIP_MEMORY_SCOPE_AGENT);
}
__device__ __forceinline__ unsigned long long ald64(const void* p) {
  return __hip_atomic_load((const unsigned long long*)p, __ATOMIC_RELAXED,
                           __HIP_MEMORY_SCOPE_AGENT);
}
__device__ __forceinline__ void ast32(void* p, unsigned v) {
  __hip_atomic_store((unsigned*)p, v, __ATOMIC_RELAXED, __HIP_MEMORY_SCOPE_AGENT);
}
__device__ __forceinline__ bf16x8 ldh(const unsigned short* p) {  // 16B via 2x8B IC loads
  union { bf16x8 v; unsigned long long q[2]; } u;
  u.q[0] = ald64(p);
  u.q[1] = ald64(p + 4);
  return u.v;
}
// 16B store straight through to IC (sc1). Compiler does not track asm vmcnt:
// every use site is followed by an explicit "s_waitcnt vmcnt(0)" before the
// syncthreads that gates the arrival flag.
__device__ __forceinline__ void st16_sc1(void* p, u32x4 v) {
  asm volatile("global_store_dwordx4 %0, %1, off sc1" :: "v"(p), "v"(v) : "memory");
}

__device__ __forceinline__ unsigned wave_min(unsigned v) {
#pragma unroll
  for (int o = 32; o > 0; o >>= 1) {
    unsigned t = (unsigned)__shfl_xor((int)v, o);
    v = t < v ? t : v;
  }
  return v;
}

// ---------------------------------------------------------------------------
__global__ void fallback_k(float* out, unsigned wsmb) { *out = -(float)wsmb; }

__global__ void cvt_bf16(const float* __restrict__ in, unsigned short* __restrict__ out, int n) {
  int i = (blockIdx.x * 256 + threadIdx.x) * 4;
  if (i < n) {
    float4 v = *(const float4*)(in + i);
    ushort4 o;
    o.x = f2bf(v.x); o.y = f2bf(v.y); o.z = f2bf(v.z); o.w = f2bf(v.w);
    *(ushort4*)(out + i) = o;
  }
}

__global__ void add_vec(const float* __restrict__ a, const float* __restrict__ b,
                        float* __restrict__ o, int n) {
  int i = blockIdx.x * 256 + threadIdx.x;
  if (i < n) o[i] = a[i] + b[i];
}

// ---------------------------------------------------------------------------
// Fused 2-layer persistent scan, 4-deep rings, split waits, weights in LDS.
// Ring: [4 slabs][64 batches][1024] bf16 (slab = 65536 ushorts).
// Slab discipline: h[s] written to slab s&3, h[s-1] read from slab (s+3)&3.
// Flag semantics (per block, monotonic): 1 = init done (slab 3 zeroed),
// s+2 = step s done (data in IC).
// Wait conditions:
//   L0 step s: own >= s+1 (read h0[s-1]); other >= s-2 for s>=4 (store gate:
//              L1 finished s-4, whose h0[s-4] lives in the slab we overwrite).
//   L1 step s: own >= s+1 (read h1[s-1]); then other >= s+2 (read h0[s]).
#define BS(mi, ks)  (*(const bf16x8*)&Bsm[(((mi)*2048 + (ks)*64 + lane)) * 8])
#define WS0(mi, ks) (*(const bf16x8*)&Bsm[32768 + (((mi)*1024 + (ks)*64 + lane)) * 8])
#define WS1(mi, ks) (*(const bf16x8*)&Bsm[32768 + (((mi)*2048 + (ks)*64 + lane)) * 8])

__global__ __launch_bounds__(256, 1) void lstm_fused(
    const float* __restrict__ x,              // [64][512][512] fp32 (fallback)
    const unsigned short* __restrict__ xb,    // [64][512][512] bf16 (or null)
    const unsigned short* __restrict__ Whh0b, const unsigned short* __restrict__ Wih0b,
    const unsigned short* __restrict__ Whh1b, const unsigned short* __restrict__ Wih1b,
    const float* __restrict__ bias0, const float* __restrict__ bias1,
    unsigned short* __restrict__ h1_all,      // [64][512][1024] bf16
    unsigned short* h0r, unsigned short* h1r, // [4][64][1024] rings
    unsigned* flags)   // [0..127]=L0 arrivals, [128..255]=L1 arrivals
{
  extern __shared__ __align__(16) unsigned short Bsm[];
  const int tid = threadIdx.x;
  const int lane = tid & 63;
  const int w = tid >> 6;            // wave = 16-batch tile
  const int c16 = lane & 15, rg = lane >> 4;
  const bool is1 = blockIdx.x >= 128;
  const int bid = is1 ? (int)blockIdx.x - 128 : (int)blockIdx.x;
  const int j0 = bid * 8;
  unsigned* fown = flags + (is1 ? 128 : 0);
  unsigned* foth = flags + (is1 ? 0 : 128);

  // ---- LDS: Whh A-frags. unit u = mi*2048 + ks*64 + ln; ln is the MFMA lane:
  // m=ln&15 -> (gate=m&3, jj=m>>2); k = ks*32 + (ln>>4)*8.
  {
    const unsigned short* W = is1 ? Whh1b : Whh0b;
    for (int u = tid; u < 4096; u += 256) {
      int mi = u >> 11;
      int ks = (u >> 6) & 31;
      int ln = u & 63;
      int m = ln & 15;
      long row = (long)(m & 3) * 1024 + j0 + mi * 4 + (m >> 2);
      *(bf16x8*)&Bsm[u * 8] = *(const bf16x8*)(W + row * 1024 + ks * 32 + (ln >> 4) * 8);
    }
  }
  // ---- LDS: Wih A-frags (same fragment scheme; K=512 for L0, K=1024 for L1) --
  if (is1) {
    for (int u = tid; u < 4096; u += 256) {
      int mi = u >> 11;
      int ks = (u >> 6) & 31;
      int ln = u & 63;
      int m = ln & 15;
      long row = (long)(m & 3) * 1024 + j0 + mi * 4 + (m >> 2);
      *(bf16x8*)&Bsm[32768 + u * 8] =
          *(const bf16x8*)(Wih1b + row * 1024 + ks * 32 + (ln >> 4) * 8);
    }
  } else {
    for (int u = tid; u < 2048; u += 256) {
      int mi = u >> 10;
      int ks = (u >> 6) & 15;
      int ln = u & 63;
      int m = ln & 15;
      long row = (long)(m & 3) * 1024 + j0 + mi * 4 + (m >> 2);
      *(bf16x8*)&Bsm[32768 + u * 8] =
          *(const bf16x8*)(Wih0b + row * 512 + ks * 32 + (ln >> 4) * 8);
    }
  }
  // ---- biases ----
  const float* bias = is1 ? bias1 : bias0;
  float bs[2][4];
#pragma unroll
  for (int mi = 0; mi < 2; ++mi)
#pragma unroll
    for (int r = 0; r < 4; ++r) bs[mi][r] = bias[r * 1024 + j0 + mi * 4 + rg];

  // ---- zero own slice of slab 3 of own ring (read as h[-1]) ----
  unsigned short* ring = is1 ? h1r : h0r;
  if (tid < 64) {
    u32x4 z = {0u, 0u, 0u, 0u};
    st16_sc1(ring + 3 * 65536 + tid * 1024 + j0, z);
  }
  asm volatile("s_waitcnt vmcnt(0)" ::: "memory");
  __syncthreads();
  if (tid == 0) ast32(fown + bid, 1u);    // init arrival

  const int boff = (w * 16 + c16) * 1024;
  const int koffbase = rg * 8;
  const int b = w * 16 + c16;
  float cst[2] = {0.f, 0.f};
  const f32x4 fz = {0.f, 0.f, 0.f, 0.f};

  if (!is1) {
    // ================= layer 0 =================
    for (int s = 0; s < 512; ++s) {
      // ---- x-part MFMA: no cross-block dependency, runs before the wait ----
      f32x4 aI0 = fz, aI1 = fz;
      if (xb) {
        const unsigned short* xp =
            xb + ((long)b * 512 + s) * 512 + koffbase;
#pragma unroll
        for (int ks = 0; ks < 16; ++ks) {
          bf16x8 xv = *(const bf16x8*)(xp + ks * 32);
          aI0 = mfma16(WS0(0, ks), xv, aI0);
          aI1 = mfma16(WS0(1, ks), xv, aI1);
        }
      } else {
        const float* xp = x + ((long)b * 512 + s) * 512 + koffbase;
#pragma unroll
        for (int ks = 0; ks < 16; ++ks) {
          bf16x8 xv = cvt8(xp + ks * 32);
          aI0 = mfma16(WS0(0, ks), xv, aI0);
          aI1 = mfma16(WS0(1, ks), xv, aI1);
        }
      }
      // ---- wait: wave0 polls own layer, wave1 polls other layer ----
      const unsigned t_own = (unsigned)(s + 1);
      const unsigned t_oth = (s >= 4) ? (unsigned)(s - 2) : 0u;
      if (w == 0) {
        for (;;) {
          unsigned a = ald32(fown + lane);
          unsigned b2 = ald32(fown + lane + 64);
          if (wave_min(a < b2 ? a : b2) >= t_own) break;
          __builtin_amdgcn_s_sleep(1);
        }
      } else if (w == 1 && t_oth) {
        for (;;) {
          unsigned c = ald32(foth + lane);
          unsigned d = ald32(foth + lane + 64);
          if (wave_min(c < d ? c : d) >= t_oth) break;
          __builtin_amdgcn_s_sleep(1);
        }
      }
      __syncthreads();
      __atomic_signal_fence(__ATOMIC_ACQ_REL);

      // ---- h-part MFMA ----
      f32x4 aW0 = fz, aW1 = fz;
      const unsigned short* hprev = ring + ((s + 3) & 3) * 65536 + boff + koffbase;
#pragma unroll 16
      for (int ks = 0; ks < 32; ++ks) {
        bf16x8 hb = ldh(hprev + ks * 32);
        aW0 = mfma16(BS(0, ks), hb, aW0);
        aW1 = mfma16(BS(1, ks), hb, aW1);
      }
      // ---- gates, packed 16B sc1 store ----
      unsigned huv[2];
#pragma unroll
      for (int mi = 0; mi < 2; ++mi) {
        float p_i = (mi ? aW1[0] + aI1[0] : aW0[0] + aI0[0]) + bs[mi][0];
        float p_f = (mi ? aW1[1] + aI1[1] : aW0[1] + aI0[1]) + bs[mi][1];
        float p_g = (mi ? aW1[2] + aI1[2] : aW0[2] + aI0[2]) + bs[mi][2];
        float p_o = (mi ? aW1[3] + aI1[3] : aW0[3] + aI0[3]) + bs[mi][3];
        float iv = sigf(p_i);
        float fv = sigf(p_f);
        float gv = tanh_s(p_g);
        float ov = sigf(p_o);
        float cn = fv * cst[mi] + iv * gv;
        cst[mi] = cn;
        huv[mi] = (unsigned)f2bf(ov * tanh_s(cn));
      }
      unsigned p0 = (unsigned)__shfl_xor((int)huv[0], 16);
      unsigned p1 = (unsigned)__shfl_xor((int)huv[1], 16);
      unsigned w0 = huv[0] | (p0 << 16);   // valid on rg even: (j0+mi*4+rg, +1)
      unsigned w1 = huv[1] | (p1 << 16);
      unsigned q0 = (unsigned)__shfl_xor((int)w0, 32);
      unsigned q1 = (unsigned)__shfl_xor((int)w1, 32);
      if (rg == 0) {
        u32x4 v = {w0, q0, w1, q1};        // j0..j0+7
        st16_sc1(ring + (s & 3) * 65536 + b * 1024 + j0, v);
      }
      asm volatile("s_waitcnt vmcnt(0)" ::: "memory");
      __syncthreads();
      if (tid == 0) ast32(fown + bid, (unsigned)(s + 2));
    }
  } else {
    // ================= layer 1 =================
    for (int s = 0; s < 512; ++s) {
      // ---- wait A: own layer (read h1[s-1]) ----
      const unsigned t_own = (unsigned)(s + 1);
      if (w == 0) {
        for (;;) {
          unsigned a = ald32(fown + lane);
          unsigned b2 = ald32(fown + lane + 64);
          if (wave_min(a < b2 ? a : b2) >= t_own) break;
          __builtin_amdgcn_s_sleep(1);
        }
      }
      __syncthreads();
      __atomic_signal_fence(__ATOMIC_ACQ_REL);

      f32x4 aW0 = fz, aW1 = fz;
      const unsigned short* hprev = ring + ((s + 3) & 3) * 65536 + boff + koffbase;
#pragma unroll 16
      for (int ks = 0; ks < 32; ++ks) {
        bf16x8 hb = ldh(hprev + ks * 32);
        aW0 = mfma16(BS(0, ks), hb, aW0);
        aW1 = mfma16(BS(1, ks), hb, aW1);
      }
      // ---- wait B: L0 finished step s (read h0[s]); overlapped Whh1 above ----
      const unsigned t_oth = (unsigned)(s + 2);
      if (w == 0) {
        for (;;) {
          unsigned c = ald32(foth + lane);
          unsigned d = ald32(foth + lane + 64);
          if (wave_min(c < d ? c : d) >= t_oth) break;
          __builtin_amdgcn_s_sleep(1);
        }
      }
      __syncthreads();
      __atomic_signal_fence(__ATOMIC_ACQ_REL);

      f32x4 aI0 = fz, aI1 = fz;
      const unsigned short* h0p = h0r + (s & 3) * 65536 + boff + koffbase;
#pragma unroll 16
      for (int ks = 0; ks < 32; ++ks) {
        bf16x8 h0b = ldh(h0p + ks * 32);
        aI0 = mfma16(WS1(0, ks), h0b, aI0);
        aI1 = mfma16(WS1(1, ks), h0b, aI1);
      }
      // ---- gates, packed stores (ring sc1 + h1_all cached) ----
      unsigned huv[2];
#pragma unroll
      for (int mi = 0; mi < 2; ++mi) {
        float p_i = (mi ? aW1[0] + aI1[0] : aW0[0] + aI0[0]) + bs[mi][0];
        float p_f = (mi ? aW1[1] + aI1[1] : aW0[1] + aI0[1]) + bs[mi][1];
        float p_g = (mi ? aW1[2] + aI1[2] : aW0[2] + aI0[2]) + bs[mi][2];
        float p_o = (mi ? aW1[3] + aI1[3] : aW0[3] + aI0[3]) + bs[mi][3];
        float iv = sigf(p_i);
        float fv = sigf(p_f);
        float gv = tanh_s(p_g);
        float ov = sigf(p_o);
        float cn = fv * cst[mi] + iv * gv;
        cst[mi] = cn;
        huv[mi] = (unsigned)f2bf(ov * tanh_s(cn));
      }
      unsigned p0 = (unsigned)__shfl_xor((int)huv[0], 16);
      unsigned p1 = (unsigned)__shfl_xor((int)huv[1], 16);
      unsigned w0 = huv[0] | (p0 << 16);
      unsigned w1 = huv[1] | (p1 << 16);
      unsigned q0 = (unsigned)__shfl_xor((int)w0, 32);
      unsigned q1 = (unsigned)__shfl_xor((int)w1, 32);
      if (rg == 0) {
        u32x4 v = {w0, q0, w1, q1};
        st16_sc1(ring + (s & 3) * 65536 + b * 1024 + j0, v);
        *(u32x4*)(h1_all + ((long)b * 512 + s) * 1024 + j0) = v;
      }
      asm volatile("s_waitcnt vmcnt(0)" ::: "memory");
      __syncthreads();
      if (tid == 0) ast32(fown + bid, (unsigned)(s + 2));
    }
  }
}

// ---------------------------------------------------------------------------
// emissions[m][c] = h1[m][:] . fc_w[c][:] + fc_b[c], c<20 (N padded to 32).
__global__ __launch_bounds__(256) void emis_k(
    const unsigned short* __restrict__ h1, const unsigned short* __restrict__ fcw,
    const float* __restrict__ fcb, float* __restrict__ em) {
  __shared__ __align__(16) unsigned short Bsm[32768];
  const int tid = threadIdx.x;
  const int lane = tid & 63;
  const int w = tid >> 6;
  const int c16 = lane & 15, rg = lane >> 4;
  for (int u = tid; u < 4096; u += 256) {
    int tile = u >> 11;
    int ks = (u >> 6) & 31;
    int ln = u & 63;
    int n = tile * 16 + (ln & 15);
    int kb = ks * 32 + (ln >> 4) * 8;
    if (n < 20) {
      *(bf16x8*)&Bsm[u * 8] = *(const bf16x8*)(fcw + (long)n * 1024 + kb);
    } else {
#pragma unroll
      for (int j = 0; j < 8; ++j) Bsm[u * 8 + j] = 0;
    }
  }
  __syncthreads();
  const long r0 = (long)blockIdx.x * 64;
  const bf16x8* arow = (const bf16x8*)(h1 + (r0 + w * 16 + c16) * 1024 + rg * 8);
  const f32x4 fz = {0.f, 0.f, 0.f, 0.f};
  f32x4 acc0 = fz, acc1 = fz;
#pragma unroll 4
  for (int ks = 0; ks < 32; ++ks) {
    bf16x8 a = arow[ks * 4];
    acc0 = mfma16(a, *(const bf16x8*)&Bsm[(ks * 64 + lane) * 8], acc0);
    acc1 = mfma16(a, *(const bf16x8*)&Bsm[((32 + ks) * 64 + lane) * 8], acc1);
  }
#pragma unroll
  for (int r = 0; r < 4; ++r) {
    long row = r0 + w * 16 + rg * 4 + r;
    em[row * 20 + c16] = acc0[r] + fcb[c16];
    int col1 = 16 + c16;
    if (col1 < 20) em[row * 20 + col1] = acc1[r] + fcb[col1];
  }
}

// ---------------------------------------------------------------------------
// CRF NLL: one wave per batch. Lanes 0..19 hold alpha[j]; 511 serial steps.
__global__ __launch_bounds__(256) void crf_k(
    const float* __restrict__ em, const int* __restrict__ labels,
    const float* __restrict__ startt, const float* __restrict__ endt,
    const float* __restrict__ trans, float* __restrict__ out) {
  const int lane = threadIdx.x & 63;
  const int b = blockIdx.x * 4 + (threadIdx.x >> 6);
  const float NEG = -1e30f;
  const int j = lane;
  const bool act = j < 20;
  float treg[20];
#pragma unroll
  for (int i = 0; i < 20; ++i) treg[i] = act ? trans[i * 20 + j] : 0.f;
  const float* emb = em + (long)b * 512 * 20;
  const int* lab = labels + (long)b * 512;
  float alpha = act ? (startt[j] + emb[j]) : NEG;
  for (int t = 1; t < 512; ++t) {
    float mx = NEG;
#pragma unroll
    for (int i = 0; i < 20; ++i) {
      float v = __shfl(alpha, i) + treg[i];
      mx = fmaxf(mx, v);
    }
    float s = 0.f;
#pragma unroll
    for (int i = 0; i < 20; ++i) {
      float v = __shfl(alpha, i) + treg[i];
      s += __expf(v - mx);
    }
    bool m = lab[t] != -1;
    float na = emb[t * 20 + (act ? j : 0)] + mx + __logf(s);
    if (act && m) alpha = na;
  }
  float v = act ? (alpha + endt[j]) : NEG;
  float mx = v;
#pragma unroll
  for (int o = 32; o > 0; o >>= 1) mx = fmaxf(mx, __shfl_xor(mx, o));
  float s = act ? __expf(v - mx) : 0.f;
#pragma unroll
  for (int o = 32; o > 0; o >>= 1) s += __shfl_xor(s, o);
  float logZ = mx + __logf(s);
  float part = 0.f;
  int cntm = 0;
  for (int t = lane; t < 512; t += 64) cntm += (lab[t] != -1) ? 1 : 0;
  for (int t = 1 + lane; t < 512; t += 64) {
    int tg = lab[t];
    if (tg != -1) {
      int tp = lab[t - 1];
      int tgc = min(max(tg, 0), 19);
      int tpc = min(max(tp, 0), 19);
      part += trans[tpc * 20 + tgc] + emb[t * 20 + tgc];
    }
  }
#pragma unroll
  for (int o = 32; o > 0; o >>= 1) {
    part += __shfl_xor(part, o);
    cntm += __shfl_xor(cntm, o);
  }
  if (lane == 0) {
    int t0c = min(max(lab[0], 0), 19);
    float score = startt[t0c] + emb[t0c] + part;
    int last = max(cntm - 1, 0);
    int tlc = min(max(lab[last], 0), 19);
    score += endt[tlc];
    float llh = score - logZ;
    atomicAdd(out, llh * (-1.f / 64.f));
  }
}

// ---------------------------------------------------------------------------
extern "C" void kernel_launch(void* const* d_in, const int* in_sizes, int n_in,
                              void* d_out, int out_size, void* d_ws, size_t ws_size,
                              hipStream_t stream) {
  const float* x      = (const float*)d_in[0];
  const int* labels   = (const int*)d_in[1];
  const float* Wih0   = (const float*)d_in[3];
  const float* Whh0   = (const float*)d_in[4];
  const float* bih0   = (const float*)d_in[5];
  const float* bhh0   = (const float*)d_in[6];
  const float* Wih1   = (const float*)d_in[7];
  const float* Whh1   = (const float*)d_in[8];
  const float* bih1   = (const float*)d_in[9];
  const float* bhh1   = (const float*)d_in[10];
  const float* fcw    = (const float*)d_in[11];
  const float* fcb    = (const float*)d_in[12];
  const float* startt = (const float*)d_in[13];
  const float* endt   = (const float*)d_in[14];
  const float* trans  = (const float*)d_in[15];
  float* out = (float*)d_out;

  char* ws = (char*)d_ws;
  size_t off = 0;
  auto alloc = [&](size_t bytes) -> void* {
    void* p = ws + off;
    off = (off + bytes + 255) & ~(size_t)255;
    return p;
  };
  unsigned short* h1_all = (unsigned short*)alloc(33554432ull * 2);  // 64 MB
  unsigned short* Whh0_b = (unsigned short*)alloc(4194304ull * 2);
  unsigned short* Wih0_b = (unsigned short*)alloc(2097152ull * 2);
  unsigned short* Whh1_b = (unsigned short*)alloc(4194304ull * 2);
  unsigned short* Wih1_b = (unsigned short*)alloc(4194304ull * 2);
  unsigned short* fcw_b  = (unsigned short*)alloc(20480ull * 2);
  float* bias0           = (float*)alloc(4096 * 4);
  float* bias1           = (float*)alloc(4096 * 4);
  unsigned short* h0r    = (unsigned short*)alloc(262144ull * 2);  // 4 slabs
  unsigned short* h1r    = (unsigned short*)alloc(262144ull * 2);
  float* em              = (float*)alloc(32768ull * 20 * 4);
  unsigned* flags        = (unsigned*)alloc(2048);

  if (off > ws_size) {
    unsigned wsmb = (unsigned)(ws_size >> 20);
    fallback_k<<<1, 1, 0, stream>>>(out, wsmb);
    return;
  }

  // Optional bf16 copy of x (32 MB) — only if workspace allows; else the
  // fused kernel falls back to fp32 x + in-loop cvt.
  unsigned short* x_b = nullptr;
  if (off + 33554432ull + 512 <= ws_size) {
    x_b = (unsigned short*)alloc(16777216ull * 2);
  }

  hipMemsetAsync(flags, 0, 2048, stream);
  hipMemsetAsync(d_out, 0, sizeof(float), stream);

  cvt_bf16<<<4096, 256, 0, stream>>>(Whh0, Whh0_b, 4194304);
  cvt_bf16<<<2048, 256, 0, stream>>>(Wih0, Wih0_b, 2097152);
  cvt_bf16<<<4096, 256, 0, stream>>>(Whh1, Whh1_b, 4194304);
  cvt_bf16<<<4096, 256, 0, stream>>>(Wih1, Wih1_b, 4194304);
  cvt_bf16<<<20, 256, 0, stream>>>(fcw, fcw_b, 20480);
  if (x_b) cvt_bf16<<<16384, 256, 0, stream>>>(x, x_b, 16777216);
  add_vec<<<16, 256, 0, stream>>>(bih0, bhh0, bias0, 4096);
  add_vec<<<16, 256, 0, stream>>>(bih1, bhh1, bias1, 4096);

  {
    static bool attr_set = false;   // host-side only; same work every call
    if (!attr_set) {
      hipFuncSetAttribute((const void*)lstm_fused,
                          hipFuncAttributeMaxDynamicSharedMemorySize, 131072);
      attr_set = true;
    }
    void* args[] = {(void*)&x, (void*)&x_b, (void*)&Whh0_b, (void*)&Wih0_b,
                    (void*)&Whh1_b, (void*)&Wih1_b, (void*)&bias0, (void*)&bias1,
                    (void*)&h1_all, (void*)&h0r, (void*)&h1r, (void*)&flags};
    hipLaunchCooperativeKernel((void*)lstm_fused, dim3(256), dim3(256), args,
                               131072, stream);
  }
  emis_k<<<512, 256, 0, stream>>>(h1_all, fcw_b, fcb, em);
  crf_k<<<16, 256, 0, stream>>>(em, labels, startt, endt, trans, out);
}

// Round 3
// 10385.987 us; speedup vs baseline: 1.0028x; 1.0028x over previous
//
#include <hip/hip_runtime.h>
#include <hip/hip_bf16.h>
#include <stdint.h>

// ---------------------------------------------------------------------------
// 2-layer LSTM + linear + CRF NLL on MI355X.
// Round 11: two-pronged:
//  A) Batch-issued h reads: fully unrolled load phase (32x16B sc1 loads into
//     named regs, ~64 outstanding) + sched_barrier(0) + MFMA sweep. R10's
//     VGPR_Count=60 proved the old interleaved loop held only ~4 loads in
//     flight -> ~900cy IC latency serialized over 32 iters = the step time.
//  B) Wait-time instrumentation exported via counter channels:
//     L0 block 0 encodes poll-wait ticks as sc1 READS  (dFETCH = ticks*8 B).
//     L1 block 0 encodes waitA+waitB ticks as sc1 WRITES (dWRITE = ticks*1 B).
//     Baselines: WRITE 397832 KB (exact), FETCH 682.7 MB (+-150KB).
// Keep R10 skeleton otherwise (4-deep rings, split waits, packed stores,
// direct-poll barrier) - all proven passing.
// ---------------------------------------------------------------------------

typedef __bf16 bf16x8 __attribute__((ext_vector_type(8)));
typedef float f32x4 __attribute__((ext_vector_type(4)));
typedef unsigned u32x4 __attribute__((ext_vector_type(4)));

__device__ __forceinline__ f32x4 mfma16(bf16x8 a, bf16x8 b, f32x4 c) {
  return __builtin_amdgcn_mfma_f32_16x16x32_bf16(a, b, c, 0, 0, 0);
}

__device__ __forceinline__ unsigned short f2bf(float f) {
  unsigned u = __float_as_uint(f);
  u = u + 0x7fffu + ((u >> 16) & 1u);
  return (unsigned short)(u >> 16);
}
__device__ __forceinline__ float sigf(float x) { return 1.f / (1.f + __expf(-x)); }
__device__ __forceinline__ float tanh_s(float x) {
  float a = fabsf(x);
  float e = __expf(2.f * a);
  float r = 1.f - 2.f / (e + 1.f);
  return copysignf(r, x);
}
__device__ __forceinline__ bf16x8 cvt8(const float* p) {
  float4 a = *(const float4*)p;
  float4 b = *(const float4*)(p + 4);
  union { bf16x8 v; unsigned short u[8]; } r;
  r.u[0] = f2bf(a.x); r.u[1] = f2bf(a.y); r.u[2] = f2bf(a.z); r.u[3] = f2bf(a.w);
  r.u[4] = f2bf(b.x); r.u[5] = f2bf(b.y); r.u[6] = f2bf(b.z); r.u[7] = f2bf(b.w);
  return r.v;
}

// ---- agent-scope (IC-coherent) primitives ----
__device__ __forceinline__ unsigned ald32(const unsigned* p) {
  return __hip_atomic_load(p, __ATOMIC_RELAXED, __HIP_MEMORY_SCOPE_AGENT);
}
__device__ __forceinline__ unsigned long long ald64(const void* p) {
  return __hip_atomic_load((const unsigned long long*)p, __ATOMIC_RELAXED,
                           __HIP_MEMORY_SCOPE_AGENT);
}
__device__ __forceinline__ void ast32(void* p, unsigned v) {
  __hip_atomic_store((unsigned*)p, v, __ATOMIC_RELAXED, __HIP_MEMORY_SCOPE_AGENT);
}
__device__ __forceinline__ bf16x8 ldh(const unsigned short* p) {  // 16B via 2x8B IC loads
  union { bf16x8 v; unsigned long long q[2]; } u;
  u.q[0] = ald64(p);
  u.q[1] = ald64(p + 4);
  return u.v;
}
__device__ __forceinline__ void st16_sc1(void* p, u32x4 v) {
  asm volatile("global_store_dwordx4 %0, %1, off sc1" :: "v"(p), "v"(v) : "memory");
}
__device__ __forceinline__ u32x4 ld16_sc1(const void* p) {
  u32x4 v;
  asm volatile("global_load_dwordx4 %0, %1, off sc1" : "=v"(v) : "v"(p) : "memory");
  return v;
}

__device__ __forceinline__ unsigned wave_min(unsigned v) {
#pragma unroll
  for (int o = 32; o > 0; o >>= 1) {
    unsigned t = (unsigned)__shfl_xor((int)v, o);
    v = t < v ? t : v;
  }
  return v;
}

// ---------------------------------------------------------------------------
__global__ void fallback_k(float* out, unsigned wsmb) { *out = -(float)wsmb; }

__global__ void cvt_bf16(const float* __restrict__ in, unsigned short* __restrict__ out, int n) {
  int i = (blockIdx.x * 256 + threadIdx.x) * 4;
  if (i < n) {
    float4 v = *(const float4*)(in + i);
    ushort4 o;
    o.x = f2bf(v.x); o.y = f2bf(v.y); o.z = f2bf(v.z); o.w = f2bf(v.w);
    *(ushort4*)(out + i) = o;
  }
}

__global__ void add_vec(const float* __restrict__ a, const float* __restrict__ b,
                        float* __restrict__ o, int n) {
  int i = blockIdx.x * 256 + threadIdx.x;
  if (i < n) o[i] = a[i] + b[i];
}

// ---------------------------------------------------------------------------
// Ring: [4 slabs][64 batches][1024] bf16 (slab = 65536 ushorts).
// h[s] -> slab s&3; h[s-1] read from slab (s+3)&3.
// Flags (monotonic): 1 = init, s+2 = step s done (data in IC).
// Waits: L0 s: own>=s+1, other>=s-2 (s>=4). L1 s: own>=s+1, then other>=s+2.
#define BS(mi, ks)  (*(const bf16x8*)&Bsm[(((mi)*2048 + (ks)*64 + lane)) * 8])
#define WS0(mi, ks) (*(const bf16x8*)&Bsm[32768 + (((mi)*1024 + (ks)*64 + lane)) * 8])
#define WS1(mi, ks) (*(const bf16x8*)&Bsm[32768 + (((mi)*2048 + (ks)*64 + lane)) * 8])

__global__ __launch_bounds__(256, 1) void lstm_fused(
    const float* __restrict__ x,              // [64][512][512] fp32 (fallback)
    const unsigned short* __restrict__ xb,    // [64][512][512] bf16 (or null)
    const unsigned short* __restrict__ Whh0b, const unsigned short* __restrict__ Wih0b,
    const unsigned short* __restrict__ Whh1b, const unsigned short* __restrict__ Wih1b,
    const float* __restrict__ bias0, const float* __restrict__ bias1,
    unsigned short* __restrict__ h1_all,      // [64][512][1024] bf16
    unsigned short* h0r, unsigned short* h1r, // [4][64][1024] rings
    unsigned* flags,   // [0..127]=L0 arrivals, [128..255]=L1 arrivals
    unsigned* instr)   // 4MB scratch for the WRITE instrumentation channel
{
  extern __shared__ __align__(16) unsigned short Bsm[];
  const int tid = threadIdx.x;
  const int lane = tid & 63;
  const int w = tid >> 6;            // wave = 16-batch tile
  const int c16 = lane & 15, rg = lane >> 4;
  const bool is1 = blockIdx.x >= 128;
  const int bid = is1 ? (int)blockIdx.x - 128 : (int)blockIdx.x;
  const int j0 = bid * 8;
  unsigned* fown = flags + (is1 ? 128 : 0);
  unsigned* foth = flags + (is1 ? 0 : 128);

  // ---- LDS: Whh A-frags ----
  {
    const unsigned short* W = is1 ? Whh1b : Whh0b;
    for (int u = tid; u < 4096; u += 256) {
      int mi = u >> 11;
      int ks = (u >> 6) & 31;
      int ln = u & 63;
      int m = ln & 15;
      long row = (long)(m & 3) * 1024 + j0 + mi * 4 + (m >> 2);
      *(bf16x8*)&Bsm[u * 8] = *(const bf16x8*)(W + row * 1024 + ks * 32 + (ln >> 4) * 8);
    }
  }
  // ---- LDS: Wih A-frags ----
  if (is1) {
    for (int u = tid; u < 4096; u += 256) {
      int mi = u >> 11;
      int ks = (u >> 6) & 31;
      int ln = u & 63;
      int m = ln & 15;
      long row = (long)(m & 3) * 1024 + j0 + mi * 4 + (m >> 2);
      *(bf16x8*)&Bsm[32768 + u * 8] =
          *(const bf16x8*)(Wih1b + row * 1024 + ks * 32 + (ln >> 4) * 8);
    }
  } else {
    for (int u = tid; u < 2048; u += 256) {
      int mi = u >> 10;
      int ks = (u >> 6) & 15;
      int ln = u & 63;
      int m = ln & 15;
      long row = (long)(m & 3) * 1024 + j0 + mi * 4 + (m >> 2);
      *(bf16x8*)&Bsm[32768 + u * 8] =
          *(const bf16x8*)(Wih0b + row * 512 + ks * 32 + (ln >> 4) * 8);
    }
  }
  // ---- biases ----
  const float* bias = is1 ? bias1 : bias0;
  float bs[2][4];
#pragma unroll
  for (int mi = 0; mi < 2; ++mi)
#pragma unroll
    for (int r = 0; r < 4; ++r) bs[mi][r] = bias[r * 1024 + j0 + mi * 4 + rg];

  // ---- zero own slice of slab 3 of own ring (read as h[-1]) ----
  unsigned short* ring = is1 ? h1r : h0r;
  if (tid < 64) {
    u32x4 z = {0u, 0u, 0u, 0u};
    st16_sc1(ring + 3 * 65536 + tid * 1024 + j0, z);
  }
  asm volatile("s_waitcnt vmcnt(0)" ::: "memory");
  __syncthreads();
  if (tid == 0) ast32(fown + bid, 1u);    // init arrival

  const int boff = (w * 16 + c16) * 1024;
  const int koffbase = rg * 8;
  const int b = w * 16 + c16;
  float cst[2] = {0.f, 0.f};
  const f32x4 fz = {0.f, 0.f, 0.f, 0.f};
  unsigned long long wait_acc = 0;   // realtime ticks spent polling (wave 0)

  if (!is1) {
    // ================= layer 0 =================
    for (int s = 0; s < 512; ++s) {
      // ---- x-part MFMA before the wait ----
      f32x4 aI0 = fz, aI1 = fz;
      if (xb) {
        const unsigned short* xp = xb + ((long)b * 512 + s) * 512 + koffbase;
#pragma unroll
        for (int ks = 0; ks < 16; ++ks) {
          bf16x8 xv = *(const bf16x8*)(xp + ks * 32);
          aI0 = mfma16(WS0(0, ks), xv, aI0);
          aI1 = mfma16(WS0(1, ks), xv, aI1);
        }
      } else {
        const float* xp = x + ((long)b * 512 + s) * 512 + koffbase;
#pragma unroll
        for (int ks = 0; ks < 16; ++ks) {
          bf16x8 xv = cvt8(xp + ks * 32);
          aI0 = mfma16(WS0(0, ks), xv, aI0);
          aI1 = mfma16(WS0(1, ks), xv, aI1);
        }
      }
      // ---- wait: wave0 own layer (timed), wave1 other layer ----
      const unsigned t_own = (unsigned)(s + 1);
      const unsigned t_oth = (s >= 4) ? (unsigned)(s - 2) : 0u;
      if (w == 0) {
        unsigned long long t0 = __builtin_amdgcn_s_memrealtime();
        for (;;) {
          unsigned long long q = ald64(fown + 2 * lane);
          unsigned a = (unsigned)q, b2 = (unsigned)(q >> 32);
          if (wave_min(a < b2 ? a : b2) >= t_own) break;
          __builtin_amdgcn_s_sleep(1);
        }
        wait_acc += __builtin_amdgcn_s_memrealtime() - t0;
      } else if (w == 1 && t_oth) {
        for (;;) {
          unsigned long long q = ald64(foth + 2 * lane);
          unsigned c = (unsigned)q, d = (unsigned)(q >> 32);
          if (wave_min(c < d ? c : d) >= t_oth) break;
          __builtin_amdgcn_s_sleep(1);
        }
      }
      __syncthreads();
      __atomic_signal_fence(__ATOMIC_ACQ_REL);

      // ---- h-part: batch-issue ALL loads, then MFMA sweep ----
      const unsigned short* hprev = ring + ((s + 3) & 3) * 65536 + boff + koffbase;
      bf16x8 hfr[32];
#pragma unroll
      for (int ks = 0; ks < 32; ++ks) hfr[ks] = ldh(hprev + ks * 32);
      __builtin_amdgcn_sched_barrier(0);
      f32x4 aW0 = fz, aW1 = fz;
#pragma unroll
      for (int ks = 0; ks < 32; ++ks) {
        aW0 = mfma16(BS(0, ks), hfr[ks], aW0);
        aW1 = mfma16(BS(1, ks), hfr[ks], aW1);
      }
      // ---- gates, packed 16B sc1 store ----
      unsigned huv[2];
#pragma unroll
      for (int mi = 0; mi < 2; ++mi) {
        float p_i = (mi ? aW1[0] + aI1[0] : aW0[0] + aI0[0]) + bs[mi][0];
        float p_f = (mi ? aW1[1] + aI1[1] : aW0[1] + aI0[1]) + bs[mi][1];
        float p_g = (mi ? aW1[2] + aI1[2] : aW0[2] + aI0[2]) + bs[mi][2];
        float p_o = (mi ? aW1[3] + aI1[3] : aW0[3] + aI0[3]) + bs[mi][3];
        float iv = sigf(p_i);
        float fv = sigf(p_f);
        float gv = tanh_s(p_g);
        float ov = sigf(p_o);
        float cn = fv * cst[mi] + iv * gv;
        cst[mi] = cn;
        huv[mi] = (unsigned)f2bf(ov * tanh_s(cn));
      }
      unsigned p0 = (unsigned)__shfl_xor((int)huv[0], 16);
      unsigned p1 = (unsigned)__shfl_xor((int)huv[1], 16);
      unsigned w0 = huv[0] | (p0 << 16);
      unsigned w1 = huv[1] | (p1 << 16);
      unsigned q0 = (unsigned)__shfl_xor((int)w0, 32);
      unsigned q1 = (unsigned)__shfl_xor((int)w1, 32);
      if (rg == 0) {
        u32x4 v = {w0, q0, w1, q1};
        st16_sc1(ring + (s & 3) * 65536 + b * 1024 + j0, v);
      }
      asm volatile("s_waitcnt vmcnt(0)" ::: "memory");
      __syncthreads();
      if (tid == 0) ast32(fown + bid, (unsigned)(s + 2));
    }
    // ---- FETCH channel: encode block 0 wave 0 wait ticks as sc1 reads ----
    // dFETCH_bytes = ticks * 8   (n = ticks/2 loads of 16B)
    if (bid == 0 && w == 0) {
      unsigned long long n = wait_acc >> 1;
      if (n > (1ull << 20)) n = 1ull << 20;
      const u32x4* src = (const u32x4*)x;            // fp32 x: untouched, 4M x 16B
      for (unsigned long long i = lane; i < n; i += 64) {
        u32x4 v = ld16_sc1(src + (i & 0x3FFFFFull));
        asm volatile("" :: "v"(v));
      }
      asm volatile("s_waitcnt vmcnt(0)" ::: "memory");
    }
  } else {
    // ================= layer 1 =================
    for (int s = 0; s < 512; ++s) {
      // ---- wait A: own layer (timed) ----
      const unsigned t_own = (unsigned)(s + 1);
      if (w == 0) {
        unsigned long long t0 = __builtin_amdgcn_s_memrealtime();
        for (;;) {
          unsigned long long q = ald64(fown + 2 * lane);
          unsigned a = (unsigned)q, b2 = (unsigned)(q >> 32);
          if (wave_min(a < b2 ? a : b2) >= t_own) break;
          __builtin_amdgcn_s_sleep(1);
        }
        wait_acc += __builtin_amdgcn_s_memrealtime() - t0;
      }
      __syncthreads();
      __atomic_signal_fence(__ATOMIC_ACQ_REL);

      const unsigned short* hprev = ring + ((s + 3) & 3) * 65536 + boff + koffbase;
      bf16x8 hfr[32];
#pragma unroll
      for (int ks = 0; ks < 32; ++ks) hfr[ks] = ldh(hprev + ks * 32);
      __builtin_amdgcn_sched_barrier(0);
      f32x4 aW0 = fz, aW1 = fz;
#pragma unroll
      for (int ks = 0; ks < 32; ++ks) {
        aW0 = mfma16(BS(0, ks), hfr[ks], aW0);
        aW1 = mfma16(BS(1, ks), hfr[ks], aW1);
      }
      // ---- wait B: L0 finished step s (timed) ----
      const unsigned t_oth = (unsigned)(s + 2);
      if (w == 0) {
        unsigned long long t0 = __builtin_amdgcn_s_memrealtime();
        for (;;) {
          unsigned long long q = ald64(foth + 2 * lane);
          unsigned c = (unsigned)q, d = (unsigned)(q >> 32);
          if (wave_min(c < d ? c : d) >= t_oth) break;
          __builtin_amdgcn_s_sleep(1);
        }
        wait_acc += __builtin_amdgcn_s_memrealtime() - t0;
      }
      __syncthreads();
      __atomic_signal_fence(__ATOMIC_ACQ_REL);

      const unsigned short* h0p = h0r + (s & 3) * 65536 + boff + koffbase;
      bf16x8 gfr[32];
#pragma unroll
      for (int ks = 0; ks < 32; ++ks) gfr[ks] = ldh(h0p + ks * 32);
      __builtin_amdgcn_sched_barrier(0);
      f32x4 aI0 = fz, aI1 = fz;
#pragma unroll
      for (int ks = 0; ks < 32; ++ks) {
        aI0 = mfma16(WS1(0, ks), gfr[ks], aI0);
        aI1 = mfma16(WS1(1, ks), gfr[ks], aI1);
      }
      // ---- gates, packed stores ----
      unsigned huv[2];
#pragma unroll
      for (int mi = 0; mi < 2; ++mi) {
        float p_i = (mi ? aW1[0] + aI1[0] : aW0[0] + aI0[0]) + bs[mi][0];
        float p_f = (mi ? aW1[1] + aI1[1] : aW0[1] + aI0[1]) + bs[mi][1];
        float p_g = (mi ? aW1[2] + aI1[2] : aW0[2] + aI0[2]) + bs[mi][2];
        float p_o = (mi ? aW1[3] + aI1[3] : aW0[3] + aI0[3]) + bs[mi][3];
        float iv = sigf(p_i);
        float fv = sigf(p_f);
        float gv = tanh_s(p_g);
        float ov = sigf(p_o);
        float cn = fv * cst[mi] + iv * gv;
        cst[mi] = cn;
        huv[mi] = (unsigned)f2bf(ov * tanh_s(cn));
      }
      unsigned p0 = (unsigned)__shfl_xor((int)huv[0], 16);
      unsigned p1 = (unsigned)__shfl_xor((int)huv[1], 16);
      unsigned w0 = huv[0] | (p0 << 16);
      unsigned w1 = huv[1] | (p1 << 16);
      unsigned q0 = (unsigned)__shfl_xor((int)w0, 32);
      unsigned q1 = (unsigned)__shfl_xor((int)w1, 32);
      if (rg == 0) {
        u32x4 v = {w0, q0, w1, q1};
        st16_sc1(ring + (s & 3) * 65536 + b * 1024 + j0, v);
        *(u32x4*)(h1_all + ((long)b * 512 + s) * 1024 + j0) = v;
      }
      asm volatile("s_waitcnt vmcnt(0)" ::: "memory");
      __syncthreads();
      if (tid == 0) ast32(fown + bid, (unsigned)(s + 2));
    }
    // ---- WRITE channel: encode block 128 wave 0 wait ticks as sc1 writes ----
    // dWRITE_bytes = ticks * 1   (n = ticks/16 stores of 16B)
    if (bid == 0 && w == 0) {
      unsigned long long n = wait_acc >> 4;
      if (n > (1ull << 20)) n = 1ull << 20;
      u32x4 v = {0x5a5a5a5au, 0u, 0u, 0u};
      for (unsigned long long i = lane; i < n; i += 64) {
        st16_sc1((char*)instr + (i & 0x3FFFFull) * 16, v);
      }
      asm volatile("s_waitcnt vmcnt(0)" ::: "memory");
    }
  }
}

// ---------------------------------------------------------------------------
// emissions[m][c] = h1[m][:] . fc_w[c][:] + fc_b[c], c<20 (N padded to 32).
__global__ __launch_bounds__(256) void emis_k(
    const unsigned short* __restrict__ h1, const unsigned short* __restrict__ fcw,
    const float* __restrict__ fcb, float* __restrict__ em) {
  __shared__ __align__(16) unsigned short Bsm[32768];
  const int tid = threadIdx.x;
  const int lane = tid & 63;
  const int w = tid >> 6;
  const int c16 = lane & 15, rg = lane >> 4;
  for (int u = tid; u < 4096; u += 256) {
    int tile = u >> 11;
    int ks = (u >> 6) & 31;
    int ln = u & 63;
    int n = tile * 16 + (ln & 15);
    int kb = ks * 32 + (ln >> 4) * 8;
    if (n < 20) {
      *(bf16x8*)&Bsm[u * 8] = *(const bf16x8*)(fcw + (long)n * 1024 + kb);
    } else {
#pragma unroll
      for (int j = 0; j < 8; ++j) Bsm[u * 8 + j] = 0;
    }
  }
  __syncthreads();
  const long r0 = (long)blockIdx.x * 64;
  const bf16x8* arow = (const bf16x8*)(h1 + (r0 + w * 16 + c16) * 1024 + rg * 8);
  const f32x4 fz = {0.f, 0.f, 0.f, 0.f};
  f32x4 acc0 = fz, acc1 = fz;
#pragma unroll 4
  for (int ks = 0; ks < 32; ++ks) {
    bf16x8 a = arow[ks * 4];
    acc0 = mfma16(a, *(const bf16x8*)&Bsm[(ks * 64 + lane) * 8], acc0);
    acc1 = mfma16(a, *(const bf16x8*)&Bsm[((32 + ks) * 64 + lane) * 8], acc1);
  }
#pragma unroll
  for (int r = 0; r < 4; ++r) {
    long row = r0 + w * 16 + rg * 4 + r;
    em[row * 20 + c16] = acc0[r] + fcb[c16];
    int col1 = 16 + c16;
    if (col1 < 20) em[row * 20 + col1] = acc1[r] + fcb[col1];
  }
}

// ---------------------------------------------------------------------------
// CRF NLL: one wave per batch. Lanes 0..19 hold alpha[j]; 511 serial steps.
__global__ __launch_bounds__(256) void crf_k(
    const float* __restrict__ em, const int* __restrict__ labels,
    const float* __restrict__ startt, const float* __restrict__ endt,
    const float* __restrict__ trans, float* __restrict__ out) {
  const int lane = threadIdx.x & 63;
  const int b = blockIdx.x * 4 + (threadIdx.x >> 6);
  const float NEG = -1e30f;
  const int j = lane;
  const bool act = j < 20;
  float treg[20];
#pragma unroll
  for (int i = 0; i < 20; ++i) treg[i] = act ? trans[i * 20 + j] : 0.f;
  const float* emb = em + (long)b * 512 * 20;
  const int* lab = labels + (long)b * 512;
  float alpha = act ? (startt[j] + emb[j]) : NEG;
  for (int t = 1; t < 512; ++t) {
    float mx = NEG;
#pragma unroll
    for (int i = 0; i < 20; ++i) {
      float v = __shfl(alpha, i) + treg[i];
      mx = fmaxf(mx, v);
    }
    float s = 0.f;
#pragma unroll
    for (int i = 0; i < 20; ++i) {
      float v = __shfl(alpha, i) + treg[i];
      s += __expf(v - mx);
    }
    bool m = lab[t] != -1;
    float na = emb[t * 20 + (act ? j : 0)] + mx + __logf(s);
    if (act && m) alpha = na;
  }
  float v = act ? (alpha + endt[j]) : NEG;
  float mx = v;
#pragma unroll
  for (int o = 32; o > 0; o >>= 1) mx = fmaxf(mx, __shfl_xor(mx, o));
  float s = act ? __expf(v - mx) : 0.f;
#pragma unroll
  for (int o = 32; o > 0; o >>= 1) s += __shfl_xor(s, o);
  float logZ = mx + __logf(s);
  float part = 0.f;
  int cntm = 0;
  for (int t = lane; t < 512; t += 64) cntm += (lab[t] != -1) ? 1 : 0;
  for (int t = 1 + lane; t < 512; t += 64) {
    int tg = lab[t];
    if (tg != -1) {
      int tp = lab[t - 1];
      int tgc = min(max(tg, 0), 19);
      int tpc = min(max(tp, 0), 19);
      part += trans[tpc * 20 + tgc] + emb[t * 20 + tgc];
    }
  }
#pragma unroll
  for (int o = 32; o > 0; o >>= 1) {
    part += __shfl_xor(part, o);
    cntm += __shfl_xor(cntm, o);
  }
  if (lane == 0) {
    int t0c = min(max(lab[0], 0), 19);
    float score = startt[t0c] + emb[t0c] + part;
    int last = max(cntm - 1, 0);
    int tlc = min(max(lab[last], 0), 19);
    score += endt[tlc];
    float llh = score - logZ;
    atomicAdd(out, llh * (-1.f / 64.f));
  }
}

// ---------------------------------------------------------------------------
extern "C" void kernel_launch(void* const* d_in, const int* in_sizes, int n_in,
                              void* d_out, int out_size, void* d_ws, size_t ws_size,
                              hipStream_t stream) {
  const float* x      = (const float*)d_in[0];
  const int* labels   = (const int*)d_in[1];
  const float* Wih0   = (const float*)d_in[3];
  const float* Whh0   = (const float*)d_in[4];
  const float* bih0   = (const float*)d_in[5];
  const float* bhh0   = (const float*)d_in[6];
  const float* Wih1   = (const float*)d_in[7];
  const float* Whh1   = (const float*)d_in[8];
  const float* bih1   = (const float*)d_in[9];
  const float* bhh1   = (const float*)d_in[10];
  const float* fcw    = (const float*)d_in[11];
  const float* fcb    = (const float*)d_in[12];
  const float* startt = (const float*)d_in[13];
  const float* endt   = (const float*)d_in[14];
  const float* trans  = (const float*)d_in[15];
  float* out = (float*)d_out;

  char* ws = (char*)d_ws;
  size_t off = 0;
  auto alloc = [&](size_t bytes) -> void* {
    void* p = ws + off;
    off = (off + bytes + 255) & ~(size_t)255;
    return p;
  };
  unsigned short* h1_all = (unsigned short*)alloc(33554432ull * 2);  // 64 MB
  unsigned short* Whh0_b = (unsigned short*)alloc(4194304ull * 2);
  unsigned short* Wih0_b = (unsigned short*)alloc(2097152ull * 2);
  unsigned short* Whh1_b = (unsigned short*)alloc(4194304ull * 2);
  unsigned short* Wih1_b = (unsigned short*)alloc(4194304ull * 2);
  unsigned short* fcw_b  = (unsigned short*)alloc(20480ull * 2);
  float* bias0           = (float*)alloc(4096 * 4);
  float* bias1           = (float*)alloc(4096 * 4);
  unsigned short* h0r    = (unsigned short*)alloc(262144ull * 2);  // 4 slabs
  unsigned short* h1r    = (unsigned short*)alloc(262144ull * 2);
  float* em              = (float*)alloc(32768ull * 20 * 4);
  unsigned* flags        = (unsigned*)alloc(2048);
  unsigned* instr        = (unsigned*)alloc(4194304);              // 4 MB

  if (off > ws_size) {
    unsigned wsmb = (unsigned)(ws_size >> 20);
    fallback_k<<<1, 1, 0, stream>>>(out, wsmb);
    return;
  }

  // Optional bf16 copy of x (32 MB)
  unsigned short* x_b = nullptr;
  if (off + 33554432ull + 512 <= ws_size) {
    x_b = (unsigned short*)alloc(16777216ull * 2);
  }

  hipMemsetAsync(flags, 0, 2048, stream);
  hipMemsetAsync(d_out, 0, sizeof(float), stream);

  cvt_bf16<<<4096, 256, 0, stream>>>(Whh0, Whh0_b, 4194304);
  cvt_bf16<<<2048, 256, 0, stream>>>(Wih0, Wih0_b, 2097152);
  cvt_bf16<<<4096, 256, 0, stream>>>(Whh1, Whh1_b, 4194304);
  cvt_bf16<<<4096, 256, 0, stream>>>(Wih1, Wih1_b, 4194304);
  cvt_bf16<<<20, 256, 0, stream>>>(fcw, fcw_b, 20480);
  if (x_b) cvt_bf16<<<16384, 256, 0, stream>>>(x, x_b, 16777216);
  add_vec<<<16, 256, 0, stream>>>(bih0, bhh0, bias0, 4096);
  add_vec<<<16, 256, 0, stream>>>(bih1, bhh1, bias1, 4096);

  {
    static bool attr_set = false;   // host-side only; same work every call
    if (!attr_set) {
      hipFuncSetAttribute((const void*)lstm_fused,
                          hipFuncAttributeMaxDynamicSharedMemorySize, 131072);
      attr_set = true;
    }
    void* args[] = {(void*)&x, (void*)&x_b, (void*)&Whh0_b, (void*)&Wih0_b,
                    (void*)&Whh1_b, (void*)&Wih1_b, (void*)&bias0, (void*)&bias1,
                    (void*)&h1_all, (void*)&h0r, (void*)&h1r, (void*)&flags,
                    (void*)&instr};
    hipLaunchCooperativeKernel((void*)lstm_fused, dim3(256), dim3(256), args,
                               131072, stream);
  }
  emis_k<<<512, 256, 0, stream>>>(h1_all, fcw_b, fcb, em);
  crf_k<<<16, 256, 0, stream>>>(em, labels, startt, endt, trans, out);
}